// Round 5
// baseline (562.372 us; speedup 1.0000x reference)
//
#include <hip/hip_runtime.h>
#include <stdint.h>

// GPTQ (4-bit, group=128) dequant GEMM + rank-16 LoRA, fused epilogue.
// R4: (a) gemm moved to mfma_f32_32x32x16_f16 (same FLOPs in 17% less
// MFMA-pipe time; swizzle re-derived for 32-row fragments); (b) prep_xax
// rewritten: no lane-scattered global reads — conversion regs ds_write'd to
// padded per-wave LDS A-tile, laq staged via swizzled global_load_lds.

#define GM 8192      // B*S
#define GN 4096      // D_out
#define GK 4096      // D_in
#define RLORA 16
#define LSCALE 2.0f  // lora_alpha / r
#define NSLAB 128    // GK / 32

typedef __attribute__((ext_vector_type(4))) float f32x4;
typedef __attribute__((ext_vector_type(16))) float f32x16;
typedef __attribute__((ext_vector_type(8))) _Float16 half8;
typedef __attribute__((ext_vector_type(8))) uint16_t u16x8;
typedef __attribute__((ext_vector_type(4))) uint16_t u16x4;

#define BAR() asm volatile("s_barrier" ::: "memory")
#define VMCNT8() do { asm volatile("s_waitcnt vmcnt(8)" ::: "memory"); \
                      __builtin_amdgcn_sched_barrier(0); } while (0)
#define VMCNT0() do { asm volatile("s_waitcnt vmcnt(0)" ::: "memory"); \
                      __builtin_amdgcn_sched_barrier(0); } while (0)
#define WAITALL() do { asm volatile("s_waitcnt vmcnt(0) lgkmcnt(0)" ::: "memory"); \
                       __builtin_amdgcn_sched_barrier(0); } while (0)

__device__ __forceinline__ uint16_t f2h(float f) {
  union { _Float16 h; uint16_t u; } c;
  c.h = (_Float16)f;
  return c.u;
}

__device__ __forceinline__ void async16(const void* g, void* l) {
  __builtin_amdgcn_global_load_lds(
      (const __attribute__((address_space(1))) void*)g,
      (__attribute__((address_space(3))) void*)l, 16, 0, 0);
}

// ---- prepass 1: qweight [K][N] -> WqT [N][K] fp16 ((q-z)*s); +lA -> fp16 ----
__global__ void prep_w_k(const int* __restrict__ qw, const int* __restrict__ qz,
                         const float* __restrict__ sc, const float* __restrict__ lA,
                         uint16_t* __restrict__ wt, uint16_t* __restrict__ laq) {
  int tid = threadIdx.x;
  if (blockIdx.x >= (GK / 64) * (GN / 64)) {
    int b = blockIdx.x - (GK / 64) * (GN / 64);
#pragma unroll
    for (int i = 0; i < 32; ++i) {
      int c = b * 8192 + i * 256 + tid;   // f32x4 chunk id
      f32x4 v = ((const f32x4*)lA)[c];
      u16x4 h;
#pragma unroll
      for (int q = 0; q < 4; ++q) h[q] = f2h(v[q]);
      ((u16x4*)laq)[c] = h;
    }
    return;
  }
  __shared__ uint16_t t[64][66];
  int bn = blockIdx.x % (GN / 64);
  int bk = blockIdx.x / (GN / 64);
  int k0 = bk * 64, n0 = bn * 64;
  int g = k0 >> 7;
  int n = tid & 63;
  int kb = tid >> 6;
  int z = qz[g * GN + n0 + n];
  float s = sc[g * GN + n0 + n];
#pragma unroll
  for (int i = 0; i < 16; ++i) {
    int kk = kb + i * 4;
    int q = qw[(size_t)(k0 + kk) * GN + n0 + n];
    t[kk][n] = f2h((float)(q - z) * s);
  }
  __syncthreads();
  for (int c = tid; c < 512; c += 256) {
    int nn = c >> 3;
    int k8 = (c & 7) * 8;
    u16x8 v;
#pragma unroll
    for (int j = 0; j < 8; ++j) v[j] = t[k8 + j][nn];
    *(u16x8*)&wt[(size_t)(n0 + nn) * GK + k0 + k8] = v;
  }
}

// ---- prepass 2: x -> xq (fp16) + ax = xq . laq^T via MFMA, LDS-staged ----
// Per wave: own K-quarter, 4 chunks of 256 cols. Conversion regs are
// ds_write'd into padded A-tile [16][264] (2-way, free). laq staged into
// per-wave B-tile [16][256] via global_load_lds with ^(row&7) chunk swizzle
// (both-sides, rule #21). MFMA reads LDS only. No cross-wave sync in loop.
__global__ __launch_bounds__(256, 2) void prep_xax_k(
    const float* __restrict__ x, const uint16_t* __restrict__ laq,
    uint16_t* __restrict__ xq, float* __restrict__ axw) {
  __shared__ __align__(16) uint16_t At[4][16 * 264];
  __shared__ __align__(16) uint16_t Bt[4][16 * 256];
  __shared__ float red[4][16][17];
  int tid = threadIdx.x;
  int w = tid >> 6, lane = tid & 63;
  int m0 = blockIdx.x * 16;
  int kq = w * 1024;
  int fr = lane & 15, fk = lane >> 4;
  uint16_t* at = At[w];
  uint16_t* bt = Bt[w];
  f32x4 acc = {0.f, 0.f, 0.f, 0.f};

  // per-lane source offsets for Bt staging units
  int br = (lane >> 5);                 // used below per unit
  for (int c = 0; c < 4; ++c) {
    int kbase = kq + c * 256;
    // (a) issue B-tile loads (8 x 1KB): LDS linear, source pre-swizzled
#pragma unroll
    for (int u = 0; u < 8; ++u) {
      int pos = u * 64 + lane;          // 16B-chunk id in [16][256] tile
      int r = pos >> 5, p = pos & 31;
      async16(laq + (size_t)r * GK + kbase + ((p ^ (r & 7)) << 3),
              bt + u * 512);
    }
    // (b) convert 16 rows x 256 cols; regs -> global xq + LDS A-tile
#pragma unroll 4
    for (int i = 0; i < 16; ++i) {
      size_t off = (size_t)(m0 + i) * GK + kbase + lane * 4;
      f32x4 v = *(const f32x4*)&x[off];
      u16x4 h;
#pragma unroll
      for (int q = 0; q < 4; ++q) h[q] = f2h(v[q]);
      *(u16x4*)&xq[off] = h;
      *(u16x4*)&at[i * 264 + lane * 4] = h;
    }
    WAITALL();   // async B-tile landed; compiler tracks At ds_writes too
    // (c) 8 K-32 slabs of 16x16x32 MFMA from LDS
#pragma unroll
    for (int s = 0; s < 8; ++s) {
      half8 av = *(const half8*)&at[fr * 264 + s * 32 + fk * 8];
      half8 bv = *(const half8*)&bt[fr * 256 + (((s * 4 + fk) ^ (fr & 7)) << 3)];
      acc = __builtin_amdgcn_mfma_f32_16x16x32_f16(av, bv, acc, 0, 0, 0);
    }
  }
  (void)br;
  // C layout: col(=r) = lane&15, row(=m) = fk*4+e
#pragma unroll
  for (int e = 0; e < 4; ++e) red[w][fk * 4 + e][fr] = acc[e];
  __syncthreads();
  int row = tid >> 4, col = tid & 15;
  float sum = red[0][row][col] + red[1][row][col] +
              red[2][row][col] + red[3][row][col];
  axw[(size_t)(m0 + row) * RLORA + col] = sum;
}

// ---------------- main GEMM: 256x256, 4-stage slab ring, 8 waves, 32x32 ----------------
__global__ __launch_bounds__(512, 2) void gemm_k(
    const uint16_t* __restrict__ xq, const uint16_t* __restrict__ wt,
    const float* __restrict__ axw, const float* __restrict__ lB,
    float* __restrict__ out) {
  __shared__ __align__(16) uint16_t sA[4 * 8192];   // 4 stages x [256][32] fp16
  __shared__ __align__(16) uint16_t sB[4 * 8192];

  const int nbx = GN / 256;                 // 16
  int wg = blockIdx.x;                      // 512 total (div by 8)
  int swz = (wg & 7) * 64 + (wg >> 3);      // XCD-bijective
  int by = swz / nbx, bx = swz % nbx;
  int m0 = by * 256, n0 = bx * 256;

  int tid = threadIdx.x;
  int w = tid >> 6, lane = tid & 63;
  int wm = w >> 2, wn = w & 3;              // 2M x 4N wave grid; 128x64/wave
  int fc = lane & 31, l5 = lane >> 5;       // 32x32 frag row / k-half

  // staging: per-thread global src (inverse-swizzled), wave-uniform LDS dst
  size_t aSrc[2], bSrc[2];
  int dstOff[2];
#pragma unroll
  for (int j = 0; j < 2; ++j) {
    int c = (j * 8 + w) * 64 + lane;        // 16B-chunk id in slab
    int row = c >> 2;
    int kl = (c & 3) ^ ((row >> 2) & 3);    // inverse swizzle on source
    aSrc[j] = (size_t)(m0 + row) * GK + kl * 8;
    bSrc[j] = (size_t)(n0 + row) * GK + kl * 8;
    dstOff[j] = (j * 8 + w) * 512;
  }

  // ds_read offsets (swizzled): phys chunk = l ^ ((row>>2)&3), l = ks*2+l5
  int aOff[4][2], bOff[2][2];
#pragma unroll
  for (int mi = 0; mi < 4; ++mi)
#pragma unroll
    for (int ks = 0; ks < 2; ++ks) {
      int r = wm * 128 + mi * 32 + fc;
      int l = ks * 2 + l5;
      aOff[mi][ks] = r * 32 + (((l ^ ((r >> 2) & 3))) << 3);
    }
#pragma unroll
  for (int ni = 0; ni < 2; ++ni)
#pragma unroll
    for (int ks = 0; ks < 2; ++ks) {
      int r = wn * 64 + ni * 32 + fc;
      int l = ks * 2 + l5;
      bOff[ni][ks] = r * 32 + (((l ^ ((r >> 2) & 3))) << 3);
    }

  // prologue: stage slabs 0,1,2
#pragma unroll
  for (int t = 0; t < 3; ++t) {
    async16(xq + aSrc[0] + t * 32, sA + t * 8192 + dstOff[0]);
    async16(xq + aSrc[1] + t * 32, sA + t * 8192 + dstOff[1]);
    async16(wt + bSrc[0] + t * 32, sB + t * 8192 + dstOff[0]);
    async16(wt + bSrc[1] + t * 32, sB + t * 8192 + dstOff[1]);
  }

  f32x16 acc[4][2];
#pragma unroll
  for (int a = 0; a < 4; ++a)
#pragma unroll
    for (int b = 0; b < 2; ++b)
#pragma unroll
      for (int e = 0; e < 16; ++e) acc[a][b][e] = 0.f;

  VMCNT8();   // slab 0 landed
  BAR();

#pragma unroll 2
  for (int g = 0; g < NSLAB; ++g) {
    const uint16_t* sa = sA + (g & 3) * 8192;
    const uint16_t* sb = sB + (g & 3) * 8192;
    int t2 = g + 3;
    int tc = (t2 < NSLAB ? t2 : NSLAB - 1) * 32;  // dummy re-stage at tail
    uint16_t* dA = sA + (t2 & 3) * 8192;
    uint16_t* dB = sB + (t2 & 3) * 8192;

    // phase 0: k-step 0 reads, stage A(g+3), 8 MFMA
    half8 a0[4], b0[2];
#pragma unroll
    for (int ni = 0; ni < 2; ++ni) b0[ni] = *(const half8*)(sb + bOff[ni][0]);
#pragma unroll
    for (int mi = 0; mi < 4; ++mi) a0[mi] = *(const half8*)(sa + aOff[mi][0]);
    async16(xq + aSrc[0] + tc, dA + dstOff[0]);
    async16(xq + aSrc[1] + tc, dA + dstOff[1]);
    __builtin_amdgcn_s_setprio(1);
#pragma unroll
    for (int mi = 0; mi < 4; ++mi)
#pragma unroll
      for (int ni = 0; ni < 2; ++ni)
        acc[mi][ni] = __builtin_amdgcn_mfma_f32_32x32x16_f16(
            a0[mi], b0[ni], acc[mi][ni], 0, 0, 0);
    __builtin_amdgcn_s_setprio(0);

    // phase 1: k-step 1 reads, stage B(g+3), counted vmcnt, 8 MFMA
    half8 a1[4], b1[2];
#pragma unroll
    for (int ni = 0; ni < 2; ++ni) b1[ni] = *(const half8*)(sb + bOff[ni][1]);
#pragma unroll
    for (int mi = 0; mi < 4; ++mi) a1[mi] = *(const half8*)(sa + aOff[mi][1]);
    async16(wt + bSrc[0] + tc, dB + dstOff[0]);
    async16(wt + bSrc[1] + tc, dB + dstOff[1]);
    VMCNT8();   // slab g+1 resident before next group
    __builtin_amdgcn_s_setprio(1);
#pragma unroll
    for (int mi = 0; mi < 4; ++mi)
#pragma unroll
      for (int ni = 0; ni < 2; ++ni)
        acc[mi][ni] = __builtin_amdgcn_mfma_f32_32x32x16_f16(
            a1[mi], b1[ni], acc[mi][ni], 0, 0, 0);
    __builtin_amdgcn_s_setprio(0);
    BAR();      // single barrier per group: frees buffer (g)&3 for reuse
  }

  // ---- epilogue: drain, stage ax/lB blocks, fused LoRA + store ----
  VMCNT0();
  __syncthreads();
  float* sax = (float*)sA;    // [256][16] f32
  float* slb = (float*)sB;
  for (int c = tid; c < 1024; c += 512) {
    int row = c >> 2, q = c & 3;
    ((f32x4*)sax)[c] = *(const f32x4*)&axw[(size_t)(m0 + row) * RLORA + q * 4];
    ((f32x4*)slb)[c] = *(const f32x4*)&lB[(size_t)(n0 + row) * RLORA + q * 4];
  }
  __syncthreads();
  f32x4 lbv[2][4];
#pragma unroll
  for (int ni = 0; ni < 2; ++ni) {
    int nl = wn * 64 + ni * 32 + fc;
#pragma unroll
    for (int q = 0; q < 4; ++q) lbv[ni][q] = ((const f32x4*)&slb[nl * 16])[q];
  }
#pragma unroll
  for (int mi = 0; mi < 4; ++mi) {
#pragma unroll
    for (int e = 0; e < 16; ++e) {
      // 32x32 C/D map (m74-verified): row=(e&3)+8*(e>>2)+4*(lane>>5)
      int mr = wm * 128 + mi * 32 + (e & 3) + ((e >> 2) << 3) + (l5 << 2);
      f32x4 axq[4];
#pragma unroll
      for (int q = 0; q < 4; ++q) axq[q] = ((const f32x4*)&sax[mr * 16])[q];
      float* orow = out + (size_t)(m0 + mr) * GN + n0 + wn * 64;
#pragma unroll
      for (int ni = 0; ni < 2; ++ni) {
        float d = 0.f;
#pragma unroll
        for (int q = 0; q < 4; ++q) {
          f32x4 p = axq[q] * lbv[ni][q];
          d += p[0] + p[1] + p[2] + p[3];
        }
        orow[ni * 32 + fc] = acc[mi][ni][e] + LSCALE * d;
      }
    }
  }
}

// ---------------- fallback path (if ws too small): correct, slow ----------------
__global__ void fb_gemm_k(const float* __restrict__ x, const int* __restrict__ qw,
                          const int* __restrict__ qz, const float* __restrict__ sc,
                          float* __restrict__ out) {
  __shared__ float sx[32][33];
  int nbx = GN / 32;
  int bx = blockIdx.x % nbx, by = blockIdx.x / nbx;
  int tid = threadIdx.x;
  int tn = tid & 31, tg = tid >> 5;
  float acc[4] = {0.f, 0.f, 0.f, 0.f};
  int n = bx * 32 + tn;
  for (int k0 = 0; k0 < GK; k0 += 32) {
    for (int i = tid; i < 32 * 32; i += 256)
      sx[i >> 5][i & 31] = x[(size_t)(by * 32 + (i >> 5)) * GK + k0 + (i & 31)];
    __syncthreads();
    int g = k0 >> 7;
    float z = (float)qz[g * GN + n];
    float s = sc[g * GN + n];
    for (int kk = 0; kk < 32; ++kk) {
      float wv = ((float)qw[(size_t)(k0 + kk) * GN + n] - z) * s;
#pragma unroll
      for (int mm = 0; mm < 4; ++mm) acc[mm] += sx[tg * 4 + mm][kk] * wv;
    }
    __syncthreads();
  }
#pragma unroll
  for (int mm = 0; mm < 4; ++mm)
    out[(size_t)(by * 32 + tg * 4 + mm) * GN + n] = acc[mm];
}

__global__ void fb_lora_k(const float* __restrict__ x, const float* __restrict__ lA,
                          const float* __restrict__ lB, float* __restrict__ out) {
  int m = blockIdx.x;
  int tid = threadIdx.x;
  __shared__ float red[256];
  __shared__ float sax[RLORA];
  for (int r = 0; r < RLORA; ++r) {
    float a = 0.f;
    for (int k = tid; k < GK; k += 256)
      a += x[(size_t)m * GK + k] * lA[(size_t)r * GK + k];
    red[tid] = a;
    __syncthreads();
    for (int off2 = 128; off2 > 0; off2 >>= 1) {
      if (tid < off2) red[tid] += red[tid + off2];
      __syncthreads();
    }
    if (tid == 0) sax[r] = red[0];
    __syncthreads();
  }
  for (int nn = tid; nn < GN; nn += 256) {
    float d = 0.f;
#pragma unroll
    for (int r = 0; r < RLORA; ++r) d += sax[r] * lB[(size_t)nn * RLORA + r];
    out[(size_t)m * GN + nn] += LSCALE * d;
  }
}

extern "C" void kernel_launch(void* const* d_in, const int* in_sizes, int n_in,
                              void* d_out, int out_size, void* d_ws, size_t ws_size,
                              hipStream_t stream) {
  const float* x = (const float*)d_in[0];
  const int* qw = (const int*)d_in[1];
  const int* qz = (const int*)d_in[2];
  const float* sc = (const float*)d_in[3];
  const float* lA = (const float*)d_in[4];
  const float* lB = (const float*)d_in[5];
  float* out = (float*)d_out;

  const size_t XQ = 0;
  const size_t WT = (size_t)GM * GK * 2;                 // 64 MiB
  const size_t AX = WT + (size_t)GN * GK * 2;            // +32 MiB
  const size_t LQ = AX + (size_t)GM * RLORA * 4;         // +512 KiB
  const size_t TOT = LQ + (size_t)RLORA * GK * 2;        // +128 KiB

  if (ws_size >= TOT) {
    uint16_t* xq = (uint16_t*)((char*)d_ws + XQ);
    uint16_t* wt = (uint16_t*)((char*)d_ws + WT);
    float* ax = (float*)((char*)d_ws + AX);
    uint16_t* laq = (uint16_t*)((char*)d_ws + LQ);
    hipLaunchKernelGGL(prep_w_k, dim3((GK / 64) * (GN / 64) + 2), dim3(256), 0,
                       stream, qw, qz, sc, lA, wt, laq);
    hipLaunchKernelGGL(prep_xax_k, dim3(GM / 16), dim3(256), 0, stream,
                       x, laq, xq, ax);
    hipLaunchKernelGGL(gemm_k, dim3((GM / 256) * (GN / 256)), dim3(512), 0, stream,
                       xq, wt, ax, lB, out);
  } else {
    hipLaunchKernelGGL(fb_gemm_k, dim3((GM / 32) * (GN / 32)), dim3(256), 0, stream,
                       x, qw, qz, sc, out);
    hipLaunchKernelGGL(fb_lora_k, dim3(GM), dim3(256), 0, stream, x, lA, lB, out);
  }
}